// Round 10
// baseline (234.009 us; speedup 1.0000x reference)
//
#include <hip/hip_runtime.h>

#define N_   512
#define V_   3889
#define V3   11667      // V_*3
#define J_   35
#define NB_  20
#define PF_K 306        // 34*9
#define KP2  352        // K = [pf 306 | beta 20 | pad 26], 11 k-steps of 32
#define KS2  11
#define EP2  11776      // pdT rows
#define WROWS 3920      // wtsB rows (49*80)
#define VKS 122         // ceil(V/32) k-steps for the J-regression GEMM

typedef __attribute__((ext_vector_type(8))) short short8;
typedef __attribute__((ext_vector_type(4))) float f32x4;

__constant__ int c_parents[J_] = {0,0,1,2,3,4,5,6,7,8,9,6,11,12,13,6,15,16,17,18,
                                  16,20,21,22,23,16,25,26,27,28,29,30,16,1,1};

static __device__ __forceinline__ unsigned short f2bf(float x) {
  union { float f; unsigned int u; } v; v.f = x;
  unsigned int r = v.u + 0x7FFF + ((v.u >> 16) & 1);   // round-to-nearest-even
  return (unsigned short)(r >> 16);
}

// ===== prep A (pure layout, fine-grained): ==================================
//  A: JrT36[j][v] = Jr[v][j] (row 35 = 0)          547 blocks
//  B: wtsB[v][64] bf16 (j/v-pad zeroed)            245 blocks
//  C: pdT[e][KP2] bf16 = [pd | sd | 0] transposed  2024 blocks
//  D: JrB bf16 B-fragment layout [jt][ks][q][col][o]  92 blocks
//  E: zero vtsdJr                                   9 blocks
#define PA_JRT 547
#define PA_WTS 245
#define PA_PD  2024
#define PA_JRB 92
#define PA_Z   9
#define PA_BLOCKS (PA_JRT + PA_WTS + PA_PD + PA_JRB + PA_Z)
__global__ __launch_bounds__(256) void k_prep_a(
    const float* __restrict__ Jr,  const float* __restrict__ wts,
    const float* __restrict__ pd,  const float* __restrict__ sd,
    float* __restrict__ JrT36, unsigned short* __restrict__ wtsB,
    unsigned short* __restrict__ pdT, unsigned short* __restrict__ JrB,
    float* __restrict__ vtsdJr) {
  int b = blockIdx.x;
  int t = threadIdx.x;
  if (b < PA_JRT) {                      // ---- JrT36 ----
    int idx = b * 256 + t;
    if (idx >= 36 * V_) return;
    int j = idx / V_, v = idx % V_;
    JrT36[idx] = (j < J_) ? Jr[v * J_ + j] : 0.f;
  } else if (b < PA_JRT + PA_WTS) {      // ---- wtsB bf16 ----
    int bb = b - PA_JRT;
    int v   = bb * 16 + (t >> 4);
    int jk0 = (t & 15) * 4;
    unsigned short pk[4];
#pragma unroll
    for (int i = 0; i < 4; ++i) {
      int j = jk0 + i;
      float x = (v < V_ && j < J_) ? wts[(size_t)v * J_ + j] : 0.f;
      pk[i] = f2bf(x);
    }
    *(unsigned long long*)(wtsB + (size_t)v * 64 + jk0) = *(unsigned long long*)pk;
  } else if (b < PA_JRT + PA_WTS + PA_PD) {  // ---- pdT bf16 ----
    int pp = b - (PA_JRT + PA_WTS);
    int ec = pp % 184, o4 = pp / 184;
    int e  = ec * 64 + (t & 63);
    int oc = o4 * 4 + (t >> 6);          // 0..43
    int k0 = oc * 8;
    bool ev = e < V3;
    union { unsigned short u[8]; short8 s; } pk;
#pragma unroll
    for (int ii = 0; ii < 8; ++ii) {
      int k = k0 + ii;
      float x = 0.f;
      if (ev && k < PF_K)            x = pd[(size_t)k * V3 + e];
      else if (ev && k < PF_K + NB_) x = sd[(size_t)(k - PF_K) * V3 + e];
      pk.u[ii] = f2bf(x);
    }
    *(short8*)(pdT + (size_t)e * KP2 + k0) = pk.s;
  } else if (b < PA_JRT + PA_WTS + PA_PD + PA_JRB) {  // ---- JrB bf16 ----
    int idx = (b - PA_JRT - PA_WTS - PA_PD) * 256 + t;
    if (idx >= 3 * VKS * 4 * 16) return;
    int col = idx & 15;
    int q   = (idx >> 4) & 3;
    int ks  = (idx >> 6) % VKS;
    int jt  = (idx >> 6) / VKS;
    int j = jt * 16 + col;
    union { unsigned short u[8]; short8 s; } pk;
#pragma unroll
    for (int o = 0; o < 8; ++o) {
      int v = ks * 32 + q * 8 + o;
      float x = (v < V_ && j < J_) ? Jr[(size_t)v * J_ + j] : 0.f;
      pk.u[o] = f2bf(x);
    }
    *(short8*)(JrB + (size_t)idx * 8) = pk.s;
  } else {                               // ---- zero vtsdJr ----
    int idx = (b - PA_JRT - PA_WTS - PA_PD - PA_JRB) * 256 + t;
    if (idx < 21 * 105) vtsdJr[idx] = 0.f;
  }
}

// ===== generic J-regression GEMM: dst[n][j][c] = sum_v src[n][3v+c]*Jr[v][j]
// A gathered fp32->bf16 in-register; B = JrB (bf16 frags); K split 4 waves.
static __device__ __forceinline__ void jr_gemm(
    const float* __restrict__ src, const unsigned short* __restrict__ JrB,
    float* __restrict__ dst, int mt, int c, int t) {
  __shared__ float part[4][3][64][4];
  int wv = t >> 6, lane = t & 63;
  int q = lane >> 4, col = lane & 15;
  int n = mt * 16 + col;                 // A-row this lane gathers
  const float* s0 = src + (size_t)n * V3 + c;
  int ks0 = wv * 31;
  int ksn = (wv == 3) ? (VKS - 93) : 31;
  const short8* Bp = (const short8*)JrB;

  f32x4 acc[3];
#pragma unroll
  for (int jt = 0; jt < 3; ++jt) acc[jt] = (f32x4){0.f, 0.f, 0.f, 0.f};

#pragma unroll 2
  for (int i = 0; i < ksn; ++i) {
    int ks = ks0 + i;
    int v0 = ks * 32 + q * 8;
    union { unsigned short u[8]; short8 s; } a;
#pragma unroll
    for (int o = 0; o < 8; ++o) {
      int v = v0 + o;
      float x = (v < V_) ? s0[3 * v] : 0.f;
      a.u[o] = f2bf(x);
    }
#pragma unroll
    for (int jt = 0; jt < 3; ++jt) {
      short8 bfr = Bp[((jt * VKS + ks) * 4 + q) * 16 + col];
      acc[jt] = __builtin_amdgcn_mfma_f32_16x16x32_bf16(a.s, bfr, acc[jt], 0, 0, 0);
    }
  }
#pragma unroll
  for (int jt = 0; jt < 3; ++jt)
#pragma unroll
    for (int r = 0; r < 4; ++r) part[wv][jt][lane][r] = acc[jt][r];
  __syncthreads();
  if (t < 192) {
    int jt = t / 64, l2 = t % 64;
    int q2 = l2 >> 4, col2 = l2 & 15;
    int j = jt * 16 + col2;
    if (j < J_) {
#pragma unroll
      for (int r = 0; r < 4; ++r) {
        float s = part[0][jt][l2][r] + part[1][jt][l2][r]
                + part[2][jt][l2][r] + part[3][jt][l2][r];
        int nn = mt * 16 + q2 * 4 + r;
        dst[(size_t)nn * 105 + j * 3 + c] = s;
      }
    }
  }
}

// ===== jp: blocks<96: JpRaw = deform@Jr (MFMA); else fp32 vtsdJr tail =======
__global__ __launch_bounds__(256) void k_jp3(
    const float* __restrict__ deform, const unsigned short* __restrict__ JrB,
    const float* __restrict__ JrT36,
    const float* __restrict__ vt, const float* __restrict__ sd,
    float* __restrict__ JpRaw, float* __restrict__ vtsdJr) {
  int b = blockIdx.x;
  int t = threadIdx.x;
  if (b < 96) {
    jr_gemm(deform, JrB, JpRaw, b & 31, b >> 5, t);
  } else {
    int bb = b - 96;                     // 0..83 = 21 dims x 4 chunks
    int d = bb >> 2, ch = bb & 3;
    const float* s0 = (d == 0) ? vt : sd + (size_t)(d - 1) * V3;
    int lane = t & 63, jg = t >> 6;
    int j0 = jg * 9;
    int c0 = ch * 15, cn = (ch == 3) ? 16 : 15;   // 61 chunks of 64 v total
    float acc[9][3];
#pragma unroll
    for (int jj = 0; jj < 9; ++jj)
#pragma unroll
      for (int cc = 0; cc < 3; ++cc) acc[jj][cc] = 0.f;
#pragma unroll 2
    for (int i = 0; i < cn; ++i) {
      int v = (c0 + i) * 64 + lane;
      bool ok = v < V_;
      float jr[9];
#pragma unroll
      for (int jj = 0; jj < 9; ++jj)
        jr[jj] = ok ? JrT36[(size_t)(j0 + jj) * V_ + v] : 0.f;
      float sx = ok ? s0[3 * v + 0] : 0.f;
      float sy = ok ? s0[3 * v + 1] : 0.f;
      float sz = ok ? s0[3 * v + 2] : 0.f;
#pragma unroll
      for (int jj = 0; jj < 9; ++jj) {
        acc[jj][0] += jr[jj] * sx;
        acc[jj][1] += jr[jj] * sy;
        acc[jj][2] += jr[jj] * sz;
      }
    }
#pragma unroll
    for (int jj = 0; jj < 9; ++jj)
#pragma unroll
      for (int cc = 0; cc < 3; ++cc) {
        float v = acc[jj][cc];
#pragma unroll
        for (int off = 32; off > 0; off >>= 1)
          v += __shfl_down(v, off, 64);
        if (lane == 0) {
          int j = j0 + jj;
          if (j < J_) atomicAdd(&vtsdJr[d * 105 + j * 3 + cc], v);
        }
      }
  }
}

// ===== joints = verts @ Jr (MFMA) ===========================================
__global__ __launch_bounds__(256) void k_joints(
    const float* __restrict__ verts, const unsigned short* __restrict__ JrB,
    float* __restrict__ joints) {
  jr_gemm(verts, JrB, joints, blockIdx.x & 31, blockIdx.x >> 5, threadIdx.x);
}

// ===== Rodrigues + Jp finalize (LDS) + chain -> Rs, pfA, AwB ================
__global__ __launch_bounds__(256) void k_chain_rod(
    const float* __restrict__ theta, const float* __restrict__ JpRaw,
    const float* __restrict__ vtsdJr,
    const float* __restrict__ se,    const float* __restrict__ trans,
    const float* __restrict__ beta,
    float* __restrict__ Rs_out, unsigned short* __restrict__ pfA,
    unsigned short* __restrict__ AwB) {
  __shared__ float loc[4][J_][12];
  __shared__ float res[4][J_][12];
  __shared__ float Jp_s[4][J_][3];
  int t = threadIdx.x;
  int w = t >> 6, l = t & 63;
  int n = blockIdx.x * 4 + w;
  int mt = n >> 4, m = n & 15;

  float r[9];
  if (l < J_) {
    int j = l;
    const float* th = theta + n * (J_ * 3) + j * 3;
    float t0 = th[0], t1 = th[1], t2 = th[2];
    float angle = sqrtf(t0 * t0 + t1 * t1 + t2 * t2 + 1e-8f);
    float inv = 1.0f / angle;
    float r0 = t0 * inv, r1 = t1 * inv, r2 = t2 * inv;
    float s, c;
    sincosf(angle, &s, &c);
    float omc = 1.0f - c;
    r[0] = c + omc * r0 * r0;      r[1] = omc * r0 * r1 - s * r2;  r[2] = omc * r0 * r2 + s * r1;
    r[3] = omc * r1 * r0 + s * r2; r[4] = c + omc * r1 * r1;       r[5] = omc * r1 * r2 - s * r0;
    r[6] = omc * r2 * r0 - s * r1; r[7] = omc * r2 * r1 + s * r0;  r[8] = c + omc * r2 * r2;

    float* ro = Rs_out + (size_t)n * (J_ * 9) + j * 9;
#pragma unroll
    for (int k = 0; k < 9; ++k) ro[k] = r[k];
    if (j > 0) {
#pragma unroll
      for (int kk = 0; kk < 9; ++kk) {
        int k = (j - 1) * 9 + kk;
        float v = r[kk] - ((kk == 0 || kk == 4 || kk == 8) ? 1.0f : 0.0f);
        size_t idx = ((((size_t)mt * KS2 + (k >> 5)) * 4 + ((k >> 3) & 3)) * 16 + m) * 8 + (k & 7);
        pfA[idx] = f2bf(v);
      }
    }
    // Jp = JpRaw + vtJr + beta @ sdJr
    const float* bn = beta + n * NB_;
#pragma unroll
    for (int cc = 0; cc < 3; ++cc) {
      int jc = j * 3 + cc;
      float val = JpRaw[n * 105 + jc] + vtsdJr[jc];
#pragma unroll
      for (int bb = 0; bb < NB_; ++bb)
        val += bn[bb] * vtsdJr[(1 + bb) * 105 + jc];
      Jp_s[w][j][cc] = val;
    }
  } else {
    unsigned short* An = AwB + (size_t)n * 16 * 64 + l;
#pragma unroll
    for (int d = 0; d < 16; ++d) An[d * 64] = 0;
    if (l < 55) {
      int k = PF_K + (l - 35);
      size_t idx = ((((size_t)mt * KS2 + (k >> 5)) * 4 + ((k >> 3) & 3)) * 16 + m) * 8 + (k & 7);
      pfA[idx] = f2bf(beta[n * NB_ + (l - 35)]);
    } else {
      for (int k = PF_K + NB_ + (l - 55); k < KP2; k += 9) {
        size_t idx = ((((size_t)mt * KS2 + (k >> 5)) * 4 + ((k >> 3) & 3)) * 16 + m) * 8 + (k & 7);
        pfA[idx] = 0;
      }
    }
  }
  __syncthreads();

  if (l < J_) {
    int j = l;
    if (j == 0) {
#pragma unroll
      for (int rr = 0; rr < 3; ++rr) {
        loc[w][0][rr * 4 + 0] = r[rr * 3 + 0];
        loc[w][0][rr * 4 + 1] = r[rr * 3 + 1];
        loc[w][0][rr * 4 + 2] = r[rr * 3 + 2];
        loc[w][0][rr * 4 + 3] = Jp_s[w][0][rr];
      }
#pragma unroll
      for (int k = 0; k < 12; ++k) res[w][0][k] = loc[w][0][k];
    } else {
      int p = c_parents[j];
      float si[3], sp[3], jh[3];
#pragma unroll
      for (int cidx = 0; cidx < 3; ++cidx) {
        si[cidx] = se[n * 105 + j * 3 + cidx];
        sp[cidx] = se[n * 105 + p * 3 + cidx];
        jh[cidx] = Jp_s[w][j][cidx] - Jp_s[w][p][cidx];
      }
#pragma unroll
      for (int rr = 0; rr < 3; ++rr) {
        float invp = 1.0f / sp[rr];
        loc[w][j][rr * 4 + 0] = r[rr * 3 + 0] * si[0] * invp;
        loc[w][j][rr * 4 + 1] = r[rr * 3 + 1] * si[1] * invp;
        loc[w][j][rr * 4 + 2] = r[rr * 3 + 2] * si[2] * invp;
        loc[w][j][rr * 4 + 3] = jh[rr];
      }
    }
  }
  __syncthreads();

  for (int i = 1; i < J_; ++i) {
    if (l < 12) {
      int p = c_parents[i];
      int rr = l >> 2, cc = l & 3;
      float acc = (cc == 3) ? res[w][p][rr * 4 + 3] : 0.f;
#pragma unroll
      for (int k = 0; k < 3; ++k)
        acc += res[w][p][rr * 4 + k] * loc[w][i][k * 4 + cc];
      res[w][i][l] = acc;
    }
    __syncthreads();
  }

  if (l < J_) {
    int j = l;
    float jx = Jp_s[w][j][0];
    float jy = Jp_s[w][j][1];
    float jz = Jp_s[w][j][2];
    unsigned short* An = AwB + (size_t)n * 16 * 64 + j;
#pragma unroll
    for (int rr = 0; rr < 3; ++rr) {
      float a0 = res[w][j][rr * 4 + 0];
      float a1 = res[w][j][rr * 4 + 1];
      float a2 = res[w][j][rr * 4 + 2];
      float a3 = res[w][j][rr * 4 + 3] - (a0 * jx + a1 * jy + a2 * jz)
               + trans[n * 3 + rr];
      An[(rr * 4 + 0) * 64] = f2bf(a0);
      An[(rr * 4 + 1) * 64] = f2bf(a1);
      An[(rr * 4 + 2) * 64] = f2bf(a2);
      An[(rr * 4 + 3) * 64] = f2bf(a3);
    }
  }
}

// ===== fused: v_posed (MFMA K=352) + LDS + skin (MFMA) -> verts =============
#define LSTR 242
__global__ __launch_bounds__(256) void k_vposed_skin(
    const unsigned short* __restrict__ pfA, const unsigned short* __restrict__ pdT,
    const unsigned short* __restrict__ AwB, const unsigned short* __restrict__ wtsB,
    const float* __restrict__ vt, const float* __restrict__ deform,
    float* __restrict__ verts) {
  __shared__ float lds[64 * LSTR];
  int t = threadIdx.x;
  int wv = t >> 6, lane = t & 63;
  int q = lane >> 4, col = lane & 15;
  int bx = blockIdx.x, by = blockIdx.y;
  int mtg0 = by * 4;
  int ebase = bx * 240 + wv * 64;

  const short8* Ap = (const short8*)pfA;
  const short8* Bp = (const short8*)pdT;

  f32x4 acc[4][4];
#pragma unroll
  for (int mt = 0; mt < 4; ++mt)
#pragma unroll
    for (int et = 0; et < 4; ++et) acc[mt][et] = (f32x4){0.f, 0.f, 0.f, 0.f};

#pragma unroll
  for (int ks = 0; ks < KS2; ++ks) {
    short8 a[4];
#pragma unroll
    for (int mt = 0; mt < 4; ++mt)
      a[mt] = Ap[(((mtg0 + mt) * KS2 + ks) * 4 + q) * 16 + col];
    short8 b[4];
#pragma unroll
    for (int et = 0; et < 4; ++et)
      b[et] = Bp[(size_t)(ebase + et * 16 + col) * (KP2 / 8) + ks * 4 + q];
#pragma unroll
    for (int mt = 0; mt < 4; ++mt)
#pragma unroll
      for (int et = 0; et < 4; ++et)
        acc[mt][et] = __builtin_amdgcn_mfma_f32_16x16x32_bf16(a[mt], b[et], acc[mt][et], 0, 0, 0);
  }

#pragma unroll
  for (int et = 0; et < 4; ++et) {
    int e_loc = wv * 64 + et * 16 + col;
    int e = bx * 240 + e_loc;
    bool ev = (e < V3) && (e_loc < 240);
    float vte = ev ? vt[e] : 0.f;
#pragma unroll
    for (int mt = 0; mt < 4; ++mt) {
#pragma unroll
      for (int r = 0; r < 4; ++r) {
        int n_loc = mt * 16 + q * 4 + r;
        if (ev) {
          int n = by * 64 + n_loc;
          float df = deform[(size_t)n * V3 + e];
          lds[n_loc * LSTR + e_loc] = acc[mt][et][r] + vte + df;
        }
      }
    }
  }
  __syncthreads();

  short8 bw0[5], bw1[5];
#pragma unroll
  for (int v5 = 0; v5 < 5; ++v5) {
    int v = bx * 80 + v5 * 16 + col;
    const short8* Wp = (const short8*)(wtsB + (size_t)v * 64);
    bw0[v5] = Wp[q];
    bw1[v5] = Wp[4 + q];
  }
#pragma unroll 2
  for (int ni = 0; ni < 16; ++ni) {
    int n_loc = wv * 16 + ni;
    int n = by * 64 + n_loc;
    const short8* Aq = (const short8*)(AwB + ((size_t)n * 16 + col) * 64);
    short8 a0 = Aq[q];
    short8 a1 = Aq[4 + q];
#pragma unroll
    for (int v5 = 0; v5 < 5; ++v5) {
      f32x4 s = (f32x4){0.f, 0.f, 0.f, 0.f};
      s = __builtin_amdgcn_mfma_f32_16x16x32_bf16(a0, bw0[v5], s, 0, 0, 0);
      s = __builtin_amdgcn_mfma_f32_16x16x32_bf16(a1, bw1[v5], s, 0, 0, 0);
      int vl = v5 * 16 + col;
      int v = bx * 80 + vl;
      if (v < V_ && q < 3) {
        float x = lds[n_loc * LSTR + 3 * vl + 0];
        float y = lds[n_loc * LSTR + 3 * vl + 1];
        float z = lds[n_loc * LSTR + 3 * vl + 2];
        verts[(size_t)n * V3 + 3 * v + q] = s[0] * x + s[1] * y + s[2] * z + s[3];
      }
    }
  }
}

extern "C" void kernel_launch(void* const* d_in, const int* in_sizes, int n_in,
                              void* d_out, int out_size, void* d_ws, size_t ws_size,
                              hipStream_t stream) {
  const float* beta   = (const float*)d_in[0];
  const float* theta  = (const float*)d_in[1];
  const float* se     = (const float*)d_in[2];
  const float* deform = (const float*)d_in[3];
  const float* trans  = (const float*)d_in[4];
  const float* vt     = (const float*)d_in[5];
  const float* sd     = (const float*)d_in[6];
  const float* pd     = (const float*)d_in[7];
  const float* Jr     = (const float*)d_in[8];
  const float* wts    = (const float*)d_in[9];

  float* out    = (float*)d_out;
  float* verts  = out;
  float* joints = out + (size_t)N_ * V3;
  float* Rs     = joints + (size_t)N_ * 105;

  char* w = (char*)d_ws;
  unsigned short* pdT    = (unsigned short*)w;                   // 8,290,304 B
  unsigned short* pfA    = (unsigned short*)(w + 8290304);       //   360,448 B
  float* JpRaw  = (float*)(w + 8650752);                         //   215,040 B
  unsigned short* AwB    = (unsigned short*)(w + 8865792);       // 1,048,576 B
  float* JrT36  = (float*)(w + 9914368);                         //   560,016 B
  unsigned short* wtsB   = (unsigned short*)(w + 10474384);      //   501,760 B
  float* vtsdJr = (float*)(w + 10976144);                        //     8,820 B
  unsigned short* JrB    = (unsigned short*)(w + 10985216);      //   749,568 B

  k_prep_a<<<PA_BLOCKS, 256, 0, stream>>>(Jr, wts, pd, sd,
                                          JrT36, wtsB, pdT, JrB, vtsdJr);
  k_jp3<<<96 + 84, 256, 0, stream>>>(deform, JrB, JrT36, vt, sd, JpRaw, vtsdJr);
  k_chain_rod<<<N_ / 4, 256, 0, stream>>>(theta, JpRaw, vtsdJr, se, trans, beta,
                                          Rs, pfA, AwB);
  k_vposed_skin<<<dim3(49, 8), 256, 0, stream>>>(pfA, pdT, AwB, wtsB, vt, deform, verts);
  k_joints<<<96, 256, 0, stream>>>(verts, JrB, joints);
}